// Round 1
// baseline (1092.163 us; speedup 1.0000x reference)
//
#include <hip/hip_runtime.h>
#include <hip/hip_bf16.h>

#define N_NODES 50000
#define N_EDGES 600000
#define D_FEAT 128

// Pass 1: per-edge temporal weight w[e] = norm[e] * exp(-lam * dt[e])
__global__ void edge_weight_kernel(const float* __restrict__ dt,
                                   const float* __restrict__ norm,
                                   const float* __restrict__ decay_lam,
                                   float* __restrict__ w, int E) {
    int i = blockIdx.x * blockDim.x + threadIdx.x;
    if (i >= E) return;
    float lam = fmaxf(decay_lam[0], 0.0f) + 1e-4f;
    w[i] = norm[i] * expf(-lam * dt[i]);
}

// Pass 2: scatter-add. 32 lanes per edge, float4 per lane (128 floats/edge).
__global__ void scatter_kernel(const float* __restrict__ h,
                               const int* __restrict__ src,
                               const int* __restrict__ dst,
                               const float* __restrict__ w,
                               float* __restrict__ out, int E) {
    long long gid = (long long)blockIdx.x * blockDim.x + threadIdx.x;
    int e = (int)(gid >> 5);
    if (e >= E) return;
    int lane = (int)(gid & 31);

    int s = src[e];
    int d = dst[e];
    float we = w[e];

    const float4* hp = (const float4*)(h + (size_t)s * D_FEAT);
    float4 v = hp[lane];

    float* op = out + (size_t)d * D_FEAT + lane * 4;
    atomicAdd(op + 0, v.x * we);
    atomicAdd(op + 1, v.y * we);
    atomicAdd(op + 2, v.z * we);
    atomicAdd(op + 3, v.w * we);
}

extern "C" void kernel_launch(void* const* d_in, const int* in_sizes, int n_in,
                              void* d_out, int out_size, void* d_ws, size_t ws_size,
                              hipStream_t stream) {
    const float* h         = (const float*)d_in[0];
    const int*   src       = (const int*)d_in[1];
    const int*   dst       = (const int*)d_in[2];
    const float* dt        = (const float*)d_in[3];
    const float* norm      = (const float*)d_in[4];
    const float* decay_lam = (const float*)d_in[5];
    float* out = (float*)d_out;

    const int E = in_sizes[1];  // src count

    float* w = (float*)d_ws;  // E floats of scratch

    // Output is poisoned before every timed launch — zero it.
    hipMemsetAsync(out, 0, (size_t)out_size * sizeof(float), stream);

    {
        int threads = 256;
        int blocks = (E + threads - 1) / threads;
        edge_weight_kernel<<<blocks, threads, 0, stream>>>(dt, norm, decay_lam, w, E);
    }
    {
        long long total = (long long)E * 32;
        int threads = 256;
        long long blocks = (total + threads - 1) / threads;
        scatter_kernel<<<(int)blocks, threads, 0, stream>>>(h, src, dst, w, out, E);
    }
}

// Round 2
// 222.137 us; speedup vs baseline: 4.9166x; 4.9166x over previous
//
#include <hip/hip_runtime.h>
#include <hip/hip_bf16.h>

#define D_FEAT 128

// ---- Pass A: per-dst degree histogram ----
__global__ void degree_kernel(const int* __restrict__ dst, int* __restrict__ deg, int E) {
    int e = blockIdx.x * blockDim.x + threadIdx.x;
    if (e >= E) return;
    atomicAdd(&deg[dst[e]], 1);
}

// ---- Pass B: hierarchical exclusive scan of deg -> offs ----
__global__ void scan_blocks(const int* __restrict__ deg, int* __restrict__ offs,
                            int* __restrict__ blockSums, int N) {
    __shared__ int tmp[256];
    int tid = threadIdx.x;
    int gid = blockIdx.x * 256 + tid;
    int v = (gid < N) ? deg[gid] : 0;
    tmp[tid] = v;
    __syncthreads();
    // inclusive Hillis-Steele
    for (int off = 1; off < 256; off <<= 1) {
        int t = (tid >= off) ? tmp[tid - off] : 0;
        __syncthreads();
        tmp[tid] += t;
        __syncthreads();
    }
    if (gid < N) offs[gid] = tmp[tid] - v;          // exclusive
    if (tid == 255) blockSums[blockIdx.x] = tmp[255];
}

__global__ void scan_sums(int* __restrict__ blockSums, int* __restrict__ blockOffs, int nb) {
    __shared__ int tmp[256];
    int tid = threadIdx.x;
    int v = (tid < nb) ? blockSums[tid] : 0;
    tmp[tid] = v;
    __syncthreads();
    for (int off = 1; off < 256; off <<= 1) {
        int t = (tid >= off) ? tmp[tid - off] : 0;
        __syncthreads();
        tmp[tid] += t;
        __syncthreads();
    }
    if (tid < nb) blockOffs[tid] = tmp[tid] - v;    // exclusive
}

__global__ void scan_fixup(int* __restrict__ offs, const int* __restrict__ blockOffs,
                           int* __restrict__ cursor, int N) {
    int gid = blockIdx.x * 256 + threadIdx.x;
    if (gid >= N) return;
    int o = offs[gid] + blockOffs[blockIdx.x];
    offs[gid] = o;
    cursor[gid] = o;
}

// ---- Pass C: bucket edges by dst; fuse temporal-weight computation ----
__global__ void bucket_kernel(const int* __restrict__ src, const int* __restrict__ dst,
                              const float* __restrict__ dt, const float* __restrict__ norm,
                              const float* __restrict__ decay_lam,
                              int* __restrict__ cursor,
                              int* __restrict__ src_list, float* __restrict__ w_list, int E) {
    int e = blockIdx.x * blockDim.x + threadIdx.x;
    if (e >= E) return;
    float lam = fmaxf(decay_lam[0], 0.0f) + 1e-4f;
    float w = norm[e] * expf(-lam * dt[e]);
    int d = dst[e];
    int pos = atomicAdd(&cursor[d], 1);
    src_list[pos] = src[e];
    w_list[pos] = w;
}

// ---- Pass D: gather-accumulate. One wave (64 lanes) per node, float2/lane ----
__global__ void gather_kernel(const float* __restrict__ h,
                              const int* __restrict__ offs, const int* __restrict__ deg,
                              const int* __restrict__ src_list, const float* __restrict__ w_list,
                              float* __restrict__ out, int N) {
    int node = blockIdx.x * 4 + (threadIdx.x >> 6);
    if (node >= N) return;
    int lane = threadIdx.x & 63;
    int start = offs[node];
    int end = start + deg[node];
    float accx = 0.0f, accy = 0.0f;
    for (int j = start; j < end; ++j) {
        int s = src_list[j];
        float we = w_list[j];
        const float2* hp = (const float2*)(h + (size_t)s * D_FEAT);
        float2 v = hp[lane];
        accx += v.x * we;
        accy += v.y * we;
    }
    float2* op = (float2*)(out + (size_t)node * D_FEAT);
    float2 r; r.x = accx; r.y = accy;
    op[lane] = r;
}

extern "C" void kernel_launch(void* const* d_in, const int* in_sizes, int n_in,
                              void* d_out, int out_size, void* d_ws, size_t ws_size,
                              hipStream_t stream) {
    const float* h         = (const float*)d_in[0];
    const int*   src       = (const int*)d_in[1];
    const int*   dst       = (const int*)d_in[2];
    const float* dt        = (const float*)d_in[3];
    const float* norm      = (const float*)d_in[4];
    const float* decay_lam = (const float*)d_in[5];
    float* out = (float*)d_out;

    const int E = in_sizes[1];
    const int N = out_size / D_FEAT;
    const int nb = (N + 255) / 256;   // scan blocks

    // workspace layout
    char* ws = (char*)d_ws;
    int*   deg       = (int*)ws;                       ws += (size_t)N * 4;
    int*   offs      = (int*)ws;                       ws += (size_t)N * 4;
    int*   cursor    = (int*)ws;                       ws += (size_t)N * 4;
    int*   blockSums = (int*)ws;                       ws += 256 * 4;
    int*   blockOffs = (int*)ws;                       ws += 256 * 4;
    int*   src_list  = (int*)ws;                       ws += (size_t)E * 4;
    float* w_list    = (float*)ws;                     ws += (size_t)E * 4;

    hipMemsetAsync(deg, 0, (size_t)N * 4, stream);

    {   // degree
        int blocks = (E + 255) / 256;
        degree_kernel<<<blocks, 256, 0, stream>>>(dst, deg, E);
    }
    {   // scan
        scan_blocks<<<nb, 256, 0, stream>>>(deg, offs, blockSums, N);
        scan_sums<<<1, 256, 0, stream>>>(blockSums, blockOffs, nb);
        scan_fixup<<<nb, 256, 0, stream>>>(offs, blockOffs, cursor, N);
    }
    {   // bucket
        int blocks = (E + 255) / 256;
        bucket_kernel<<<blocks, 256, 0, stream>>>(src, dst, dt, norm, decay_lam,
                                                  cursor, src_list, w_list, E);
    }
    {   // gather (writes every output element; no out memset needed)
        int blocks = (N + 3) / 4;
        gather_kernel<<<blocks, 256, 0, stream>>>(h, offs, deg, src_list, w_list, out, N);
    }
}